// Round 11
// baseline (199.087 us; speedup 1.0000x reference)
//
#include <hip/hip_runtime.h>

// Problem constants (fixed by setup_inputs)
constexpr int B = 4;
constexpr int C = 64;    // input channels
constexpr int O = 64;    // output channels (main conv)
constexpr int OOFF = 18; // offset channels = 2*3*3
constexpr int H = 192;
constexpr int W = 192;

typedef __attribute__((ext_vector_type(8))) short short8;   // 8 bf16 = 4 VGPR
typedef __attribute__((ext_vector_type(4))) float float4v;  // MFMA acc
typedef __attribute__((ext_vector_type(2))) float f32x2;    // v_pk_fma_f32 pair
typedef __attribute__((ext_vector_type(2))) uint u32x2;
typedef __attribute__((ext_vector_type(2))) __bf16 bf16x2;

__device__ inline ushort f2bf(float f) { // RNE via HW __bf16 convert
  return __builtin_bit_cast(ushort, (__bf16)f);
}
__device__ inline uint pk2bf(float lo, float hi) { // pack 2 bf16 (RNE)
  bf16x2 v;
  v.x = (__bf16)lo;
  v.y = (__bf16)hi;
  return __builtin_bit_cast(uint, v);
}
__device__ inline f32x2 upk(uint u) { // unpack 2 bf16 -> 2 f32
  u32x2 t;
  t.x = u << 16;
  t.y = u & 0xffff0000u;
  return __builtin_bit_cast(f32x2, t);
}

// -------------------------------------------------------------------------
// Kernel PRE v3 — DRAM-granule fix. v2 read x as 64 B chunks per (c,h) at
// ~147 KB plane stride (poor HBM locality; r10 showed v1->v2 was only ~2us,
// both granule-bound). THIS REV: block = one (b,h) pair; reads each (c,h)
// row as 768 B CONTIGUOUS (12 float4 per 4-lane group), stages f32 in LDS
// [64][193], writes the (b,h) xtb slab as 24 KB contiguous (128 B/px).
// Same f2bf per element, same mapping -> bit-identical xtb.
// Blocks [768,912): wBf prep; [912,984): wOf prep (unchanged math).
// -------------------------------------------------------------------------
__global__ __launch_bounds__(256) void k_pre(const float* __restrict__ x,
                                             ushort* __restrict__ xtb,
                                             const float* __restrict__ w_conv,
                                             ushort* __restrict__ wBf,
                                             const float* __restrict__ w_off,
                                             ushort* __restrict__ wOf) {
  __shared__ float tile[64][193];
  const int bid = blockIdx.x;
  const int tid = threadIdx.x;
  if (bid < 768) { // transpose: b = bid/192, h = bid%192
    const int b = bid / 192;
    const int h = bid % 192;
    const int c = tid >> 2, q = tid & 3; // 64 c-rows x 4 lanes each
    const float* row = &x[(((size_t)b * C + c) * H + h) * W];
#pragma unroll
    for (int i = 0; i < 12; ++i) { // 4-lane group covers f4 [4i,4i+4) = 64 B contig
      const float4 v = *(const float4*)&row[(q + 4 * i) * 4];
      const int w4 = (q + 4 * i) * 4;
      tile[c][w4 + 0] = v.x;
      tile[c][w4 + 1] = v.y;
      tile[c][w4 + 2] = v.z;
      tile[c][w4 + 3] = v.w;
    }
    __syncthreads();
    // write: 32 px per pass (8 lanes/px, 16 B each), 6 passes -> 24 KB contig
    const int cg = tid & 7; // c-group: channels cg*8..cg*8+7
#pragma unroll
    for (int pass = 0; pass < 6; ++pass) {
      const int w = pass * 32 + (tid >> 3);
      uint4 u;
      u.x = pk2bf(tile[cg * 8 + 0][w], tile[cg * 8 + 1][w]);
      u.y = pk2bf(tile[cg * 8 + 2][w], tile[cg * 8 + 3][w]);
      u.z = pk2bf(tile[cg * 8 + 4][w], tile[cg * 8 + 5][w]);
      u.w = pk2bf(tile[cg * 8 + 6][w], tile[cg * 8 + 7][w]);
      *(uint4*)&xtb[(((size_t)b * H + h) * W + w) * C + cg * 8] = u;
    }
  } else if (bid < 912) { // wBf: 36864 entries (144 blocks)
    const int i = (bid - 768) * 256 + tid;
    const int j = i & 7;
    const int lane = (i >> 3) & 63;
    const int nt = (i >> 9) & 3;
    const int kstep = (i >> 11) & 1;
    const int kk = i >> 12;
    const int n = nt + 4 * (lane & 15); // permuted
    const int c = kstep * 32 + ((lane >> 4) & 3) * 8 + j;
    wBf[i] = f2bf(w_conv[((size_t)n * C + c) * 9 + kk]);
  } else { // wOf: 18432 entries (72 blocks)
    const int i = (bid - 912) * 256 + tid;
    const int j = i & 7;
    const int lane = (i >> 3) & 63;
    const int nt = (i >> 9) & 1;
    const int ks = (i >> 10) & 1;
    const int kk = i >> 11;
    const int n = nt * 16 + (lane & 15);
    const int c = ks * 32 + ((lane >> 4) & 3) * 8 + j;
    wOf[i] = (n < OOFF) ? f2bf(w_off[((size_t)n * C + c) * 9 + kk]) : (ushort)0;
  }
}

// -------------------------------------------------------------------------
// Kernel FUSED: best-measured variant VERBATIM (77.3us, r10). 2-wave
// (128-thread) blocks, grid 4608; waves fully decoupled (per-wave LDS slabs,
// no __syncthreads). Gather lane map (p=lane>>2, qtr=lane&3) preserved (r7:
// reordering costs 62% via coalescing loss). Chunk A = line 0 (bytes
// qtr*16), chunk B = line 1 (+64B). No setprio (r8: cost 7-10us).
// -------------------------------------------------------------------------
__global__ __launch_bounds__(128) void k_fused(
    const ushort* __restrict__ xtb, const ushort* __restrict__ wOf,
    const float* __restrict__ b_off, const ushort* __restrict__ wBf,
    const float* __restrict__ b_conv, ushort* __restrict__ yt) {
  __shared__ ushort sA[2][2][64][8];                // [wave][ks][row][j] = 4 KB
  __shared__ __align__(16) float offBuf[2][16][20]; // [wave][pl][oc(18,pad20)] = 2.5 KB

  const int bid = blockIdx.x;
  const int xcd = bid & 7;
  const int s0 = bid >> 3; // 0..575
  const int b = xcd >> 1;
  const int half = xcd & 1;
  const int th = s0 / 24; // 0..23
  const int tw = s0 % 24; // 0..23

  const int tid = threadIdx.x;
  const int wave = tid >> 6, lane = tid & 63;
  const int h0 = half * 96 + th * 4 + wave * 2; // this wave's 2-row band
  const int w0 = tw * 8;

  const int col = lane & 15, quad = lane >> 4;
  const int p = lane >> 2, qtr = lane & 3; // pixel 0..15, channel-quarter
  const int prow = p >> 3, pcol = p & 7;
  const int h = h0 + prow, w = w0 + pcol;

  // ===================== Phase 1: offset conv (per wave) =====================
  {
    float4v oacc[2];
#pragma unroll
    for (int nt = 0; nt < 2; ++nt) oacc[nt] = (float4v){0.f, 0.f, 0.f, 0.f};

    short8 oafr[2][2]; // [pb][ks] — A fragments double-buffered; weights inline

    auto oload = [&](int kk, int pb) {
      const int ky = kk / 3, kx = kk % 3;
      const int hh = h0 + (col >> 3) + ky - 1;
      const int ww = w0 + (col & 7) + kx - 1;
      const bool ok = ((unsigned)hh < (unsigned)H) && ((unsigned)ww < (unsigned)W);
      const int hhc = min(max(hh, 0), H - 1);
      const int wwc = min(max(ww, 0), W - 1);
      const ushort* pa = xtb + (((size_t)b * H + hhc) * W + wwc) * C + quad * 8;
#pragma unroll
      for (int ks = 0; ks < 2; ++ks) {
        short8 v = (short8)0;
        if (ok) v = *(const short8*)(pa + ks * 32);
        oafr[pb][ks] = v;
      }
    };

    oload(0, 0);
#pragma unroll 2 // keeps pb = kk&1 compile-time
    for (int kk = 0; kk < 9; ++kk) {
      const int pb = kk & 1;
      if (kk < 8) oload(kk + 1, pb ^ 1);
#pragma unroll
      for (int ks = 0; ks < 2; ++ks)
#pragma unroll
        for (int nt = 0; nt < 2; ++nt) {
          const short8 bw =
              *(const short8*)&wOf[((((size_t)kk * 2 + ks) * 2 + nt) * 64 + lane) * 8];
          oacc[nt] = __builtin_amdgcn_mfma_f32_16x16x32_bf16(oafr[pb][ks], bw, oacc[nt], 0, 0, 0);
        }
    }

    // distribute offsets: D[m=quad*4+r][n=nt*16+col] -> offBuf[wave][m][oc]
#pragma unroll
    for (int nt = 0; nt < 2; ++nt) {
      const int oc = nt * 16 + col;
      if (oc < OOFF) {
        const float bias = b_off[oc];
#pragma unroll
        for (int r = 0; r < 4; ++r)
          offBuf[wave][quad * 4 + r][oc] = oacc[nt][r] + bias;
      }
    }
  } // intra-wave LDS exchange: no barrier needed (same-wave ds ordering)

  // ===================== Phase 2: deformable conv =====================
  const ushort* xbase = xtb + (size_t)b * H * W * C;
  const uint qoff = (uint)qtr * 16u; // 16B slice within line 0 of the pixel
  const float hm1 = (float)(h - 1), wm1 = (float)(w - 1);

  uint offs[4];       // single-slot corner byte offsets (next kk to load)
  float4 awv;         // single-slot bilinear weights (current kk to blend)
  uint4 gA[4], gB[4]; // both chunks in flight a full kk ahead (32 VGPR)

  auto calc = [&](int kk) {
    const float2 ov = *(const float2*)&offBuf[wave][p][2 * kk];
    const int ky = kk / 3, kx = kk % 3;
    const float pyf = ov.x + hm1 + (float)ky;
    const float pxf = ov.y + wm1 + (float)kx;
    const float fy0 = floorf(pyf), fx0 = floorf(pxf);
    const float wy = pyf - fy0, wx = pxf - fx0;
    const int iy0 = (int)fy0, ix0 = (int)fx0;
    const int iy1 = iy0 + 1, ix1 = ix0 + 1;
    const bool vy0 = (unsigned)iy0 < (unsigned)H;
    const bool vy1 = (unsigned)iy1 < (unsigned)H;
    const bool vx0 = (unsigned)ix0 < (unsigned)W;
    const bool vx1 = (unsigned)ix1 < (unsigned)W;
    awv.x = (vy0 && vx0) ? (1.f - wy) * (1.f - wx) : 0.f;
    awv.y = (vy0 && vx1) ? (1.f - wy) * wx : 0.f;
    awv.z = (vy1 && vx0) ? wy * (1.f - wx) : 0.f;
    awv.w = (vy1 && vx1) ? wy * wx : 0.f;
    const int cy0 = min(max(iy0, 0), H - 1), cy1 = min(max(iy1, 0), H - 1);
    const int cx0 = min(max(ix0, 0), W - 1), cx1 = min(max(ix1, 0), W - 1);
    offs[0] = (uint)((cy0 * W + cx0) * (C * 2)) + qoff;
    offs[1] = (uint)((cy0 * W + cx1) * (C * 2)) + qoff;
    offs[2] = (uint)((cy1 * W + cx0) * (C * 2)) + qoff;
    offs[3] = (uint)((cy1 * W + cx1) * (C * 2)) + qoff;
  };

  auto loadAB = [&]() {
#pragma unroll
    for (int c = 0; c < 4; ++c)
      gA[c] = *(const uint4*)((const char*)xbase + offs[c]); // line 0 (ch 8q..)
#pragma unroll
    for (int c = 0; c < 4; ++c)
      gB[c] = *(const uint4*)((const char*)xbase + offs[c] + 64u); // line 1
  };
  auto blend = [&](const uint4* g, uint* pk) {
    const f32x2 a00 = {awv.x, awv.x};
    const f32x2 a01 = {awv.y, awv.y};
    const f32x2 a10 = {awv.z, awv.z};
    const f32x2 a11 = {awv.w, awv.w};
#pragma unroll
    for (int i = 0; i < 4; ++i) {
      f32x2 sv = upk(g[0][i]) * a00 + upk(g[1][i]) * a01 + upk(g[2][i]) * a10 + upk(g[3][i]) * a11;
      pk[i] = pk2bf(sv.x, sv.y);
    }
  };

  float4v acc[4];
#pragma unroll
  for (int nt = 0; nt < 4; ++nt) acc[nt] = (float4v){0.f, 0.f, 0.f, 0.f};

  calc(0);
  loadAB(); // kk=0 fully in flight
#pragma unroll
  for (int kk = 0; kk < 9; ++kk) {
    uint pkA[4];
    blend(gA, pkA); // chunk A = channels 8*qtr..8*qtr+7 (ks=0, k-group qtr)
    *(uint4*)&sA[wave][0][p | (qtr << 4)][0] = *(const uint4*)pkA;
    uint pkB[4];
    blend(gB, pkB); // chunk B = channels 32+8*qtr.. (ks=1, k-group qtr)
    *(uint4*)&sA[wave][1][p | (qtr << 4)][0] = *(const uint4*)pkB;

    if (kk < 8) {
      calc(kk + 1); // safe: awv/offs consumed above (single slot)
      loadAB();     // next kk fully in flight, covered by MFMA below
    }

    // intra-wave exchange: writes above, reads below, same wave => ordered.
#pragma unroll
    for (int ks = 0; ks < 2; ++ks) {
      const short8 a = *(const short8*)&sA[wave][ks][lane][0];
#pragma unroll
      for (int nt = 0; nt < 4; ++nt) {
        const short8 bb = *(const short8*)&wBf[((((size_t)kk * 2 + ks) * 4 + nt) * 64 + lane) * 8];
        acc[nt] = __builtin_amdgcn_mfma_f32_16x16x32_bf16(a, bb, acc[nt], 0, 0, 0);
      }
    }
  }

  // epilogue: yt[b][h][w][c] bf16, oc = nt + 4*(lane&15) (permuted)
  float bias[4];
#pragma unroll
  for (int nt = 0; nt < 4; ++nt) bias[nt] = b_conv[4 * col + nt];
#pragma unroll
  for (int r = 0; r < 4; ++r) {
    const int pp = quad * 4 + r; // pixel index in this wave's 2x8 band
    const int hrow = h0 + (pp >> 3), wcol = w0 + (pp & 7);
    uint2 u;
    u.x = pk2bf(acc[0][r] + bias[0], acc[1][r] + bias[1]);
    u.y = pk2bf(acc[2][r] + bias[2], acc[3][r] + bias[3]);
    *(uint2*)&yt[((size_t)(b * H + hrow) * W + wcol) * C + 4 * col] = u;
  }
}

// -------------------------------------------------------------------------
// Kernel 4 v4 — store-granule fix. The r2 shape writes each (oc,h) as ONE
// 64 B chunk at ~147 KB plane stride (NCHW out, 37.7 MB of 64 B-granule
// scattered DRAM writes). THIS REV: wave = 1 h x 48 w x 64 oc (3 M-tiles,
// acc[3][4]) so each (oc,h) gets 3 consecutive 64 B stores = 192 B granule.
// B-frags loaded once per kk (r8: buffering choice neutral); A-frags
// 1-kk-ahead double-buffered. Per-output (kk,ks) accumulation order
// unchanged -> bit-identical. grid (4, 48, 4) = 768 blocks, 4 waves each.
// -------------------------------------------------------------------------
__global__ __launch_bounds__(256) void k_conv_main_mfma(
    const ushort* __restrict__ yt, const ushort* __restrict__ wBf,
    const float* __restrict__ b_conv, float* __restrict__ out) {
  const int w0 = blockIdx.x * 48;
  const int b = blockIdx.z;
  const int tid = threadIdx.x;
  const int wave = tid >> 6, lane = tid & 63;
  const int col = lane & 15, quad = lane >> 4;
  const int h = blockIdx.y * 4 + wave; // one output row per wave

  float4v acc[3][4]; // [mt][nt] = 48 VGPR
#pragma unroll
  for (int mt = 0; mt < 3; ++mt)
#pragma unroll
    for (int nt = 0; nt < 4; ++nt) acc[mt][nt] = (float4v){0.f, 0.f, 0.f, 0.f};

  short8 afr[2][3][2]; // [pb][mt][ks] — A double-buffered across kk

  auto load = [&](int kk, int pb) {
    const int ky = kk / 3, kx = kk % 3;
    const int hh = h + ky - 1;
    const bool hok = (unsigned)hh < (unsigned)H;
    const int hhc = min(max(hh, 0), H - 1);
#pragma unroll
    for (int mt = 0; mt < 3; ++mt) {
      const int ww = w0 + mt * 16 + col + kx - 1;
      const bool ok = hok && ((unsigned)ww < (unsigned)W);
      const int wwc = min(max(ww, 0), W - 1);
      const ushort* pa = yt + (((size_t)b * H + hhc) * W + wwc) * C + quad * 8;
#pragma unroll
      for (int ks = 0; ks < 2; ++ks) {
        short8 v = (short8)0;
        if (ok) v = *(const short8*)(pa + ks * 32);
        afr[pb][mt][ks] = v;
      }
    }
  };

  load(0, 0);
#pragma unroll 2 // pb stays compile-time
  for (int kk = 0; kk < 9; ++kk) {
    const int pb = kk & 1;
    if (kk < 8) load(kk + 1, pb ^ 1);
#pragma unroll
    for (int ks = 0; ks < 2; ++ks)
#pragma unroll
      for (int nt = 0; nt < 4; ++nt) {
        const short8 bb = *(const short8*)&wBf[((((size_t)kk * 2 + ks) * 4 + nt) * 64 + lane) * 8];
#pragma unroll
        for (int mt = 0; mt < 3; ++mt) // bb reused 3x
          acc[mt][nt] =
              __builtin_amdgcn_mfma_f32_16x16x32_bf16(afr[pb][mt][ks], bb, acc[mt][nt], 0, 0, 0);
      }
  }

  float bias[4];
#pragma unroll
  for (int nt = 0; nt < 4; ++nt) bias[nt] = b_conv[4 * col + nt];
#pragma unroll
  for (int mt = 0; mt < 3; ++mt)
#pragma unroll
    for (int nt = 0; nt < 4; ++nt) {
      const int oc = 4 * col + nt; // permuted C/D col -> oc
      float4 v;
      v.x = acc[mt][nt][0] + bias[nt];
      v.y = acc[mt][nt][1] + bias[nt];
      v.z = acc[mt][nt][2] + bias[nt];
      v.w = acc[mt][nt][3] + bias[nt];
      *(float4*)&out[(((size_t)b * O + oc) * H + h) * W + w0 + mt * 16 + quad * 4] = v;
    }
}

// -------------------------------------------------------------------------
extern "C" void kernel_launch(void* const* d_in, const int* in_sizes, int n_in,
                              void* d_out, int out_size, void* d_ws, size_t ws_size,
                              hipStream_t stream) {
  const float* x = (const float*)d_in[0];
  const float* w_off = (const float*)d_in[1];
  const float* b_off = (const float*)d_in[2];
  const float* w_conv = (const float*)d_in[3];
  const float* b_conv = (const float*)d_in[4];
  float* out = (float*)d_out;

  ushort* xtb = (ushort*)d_ws;              // B*H*W*C bf16
  ushort* yt = xtb + (size_t)B * H * W * C; // B*H*W*C bf16
  ushort* wBf = yt + (size_t)B * H * W * C; // 36864 bf16
  ushort* wOf = wBf + 36864;                // 18432 bf16

  k_pre<<<dim3(984), dim3(256), 0, stream>>>(x, xtb, w_conv, wBf, w_off, wOf);
  k_fused<<<dim3(4608), dim3(128), 0, stream>>>(xtb, wOf, b_off, wBf, b_conv, yt);
  k_conv_main_mfma<<<dim3(W / 48, H / 4, B), dim3(256), 0, stream>>>(yt, wBf, b_conv, out);
}

// Round 12
// 190.092 us; speedup vs baseline: 1.0473x; 1.0473x over previous
//
#include <hip/hip_runtime.h>

// Problem constants (fixed by setup_inputs)
constexpr int B = 4;
constexpr int C = 64;    // input channels
constexpr int O = 64;    // output channels (main conv)
constexpr int OOFF = 18; // offset channels = 2*3*3
constexpr int H = 192;
constexpr int W = 192;

typedef __attribute__((ext_vector_type(8))) short short8;   // 8 bf16 = 4 VGPR
typedef __attribute__((ext_vector_type(4))) float float4v;  // MFMA acc
typedef __attribute__((ext_vector_type(2))) float f32x2;    // v_pk_fma_f32 pair
typedef __attribute__((ext_vector_type(2))) uint u32x2;
typedef __attribute__((ext_vector_type(2))) __bf16 bf16x2;

__device__ inline ushort f2bf(float f) { // RNE via HW __bf16 convert
  return __builtin_bit_cast(ushort, (__bf16)f);
}
__device__ inline uint pk2bf(float lo, float hi) { // pack 2 bf16 (RNE)
  bf16x2 v;
  v.x = (__bf16)lo;
  v.y = (__bf16)hi;
  return __builtin_bit_cast(uint, v);
}
__device__ inline f32x2 upk(uint u) { // unpack 2 bf16 -> 2 f32
  u32x2 t;
  t.x = u << 16;
  t.y = u & 0xffff0000u;
  return __builtin_bit_cast(f32x2, t);
}

// -------------------------------------------------------------------------
// Kernel PRE v3 (r11, kept): block = one (b,h) pair; 768 B contiguous row
// reads, LDS f32 [64][193], 24 KB contiguous slab writes. Blocks [768,912):
// wBf prep; [912,984): wOf prep. Bit-identical xtb vs all prior versions.
// (r10/r11 evidence: k_pre is <=~15us in every variant — near its floor.)
// -------------------------------------------------------------------------
__global__ __launch_bounds__(256) void k_pre(const float* __restrict__ x,
                                             ushort* __restrict__ xtb,
                                             const float* __restrict__ w_conv,
                                             ushort* __restrict__ wBf,
                                             const float* __restrict__ w_off,
                                             ushort* __restrict__ wOf) {
  __shared__ float tile[64][193];
  const int bid = blockIdx.x;
  const int tid = threadIdx.x;
  if (bid < 768) { // transpose: b = bid/192, h = bid%192
    const int b = bid / 192;
    const int h = bid % 192;
    const int c = tid >> 2, q = tid & 3; // 64 c-rows x 4 lanes each
    const float* row = &x[(((size_t)b * C + c) * H + h) * W];
#pragma unroll
    for (int i = 0; i < 12; ++i) { // 4-lane group covers f4 [4i,4i+4) = 64 B contig
      const float4 v = *(const float4*)&row[(q + 4 * i) * 4];
      const int w4 = (q + 4 * i) * 4;
      tile[c][w4 + 0] = v.x;
      tile[c][w4 + 1] = v.y;
      tile[c][w4 + 2] = v.z;
      tile[c][w4 + 3] = v.w;
    }
    __syncthreads();
    // write: 32 px per pass (8 lanes/px, 16 B each), 6 passes -> 24 KB contig
    const int cg = tid & 7; // c-group: channels cg*8..cg*8+7
#pragma unroll
    for (int pass = 0; pass < 6; ++pass) {
      const int w = pass * 32 + (tid >> 3);
      uint4 u;
      u.x = pk2bf(tile[cg * 8 + 0][w], tile[cg * 8 + 1][w]);
      u.y = pk2bf(tile[cg * 8 + 2][w], tile[cg * 8 + 3][w]);
      u.z = pk2bf(tile[cg * 8 + 4][w], tile[cg * 8 + 5][w]);
      u.w = pk2bf(tile[cg * 8 + 6][w], tile[cg * 8 + 7][w]);
      *(uint4*)&xtb[(((size_t)b * H + h) * W + w) * C + cg * 8] = u;
    }
  } else if (bid < 912) { // wBf: 36864 entries (144 blocks)
    const int i = (bid - 768) * 256 + tid;
    const int j = i & 7;
    const int lane = (i >> 3) & 63;
    const int nt = (i >> 9) & 3;
    const int kstep = (i >> 11) & 1;
    const int kk = i >> 12;
    const int n = nt + 4 * (lane & 15); // permuted
    const int c = kstep * 32 + ((lane >> 4) & 3) * 8 + j;
    wBf[i] = f2bf(w_conv[((size_t)n * C + c) * 9 + kk]);
  } else { // wOf: 18432 entries (72 blocks)
    const int i = (bid - 912) * 256 + tid;
    const int j = i & 7;
    const int lane = (i >> 3) & 63;
    const int nt = (i >> 9) & 1;
    const int ks = (i >> 10) & 1;
    const int kk = i >> 11;
    const int n = nt * 16 + (lane & 15);
    const int c = ks * 32 + ((lane >> 4) & 3) * 8 + j;
    wOf[i] = (n < OOFF) ? f2bf(w_off[((size_t)n * C + c) * 9 + kk]) : (ushort)0;
  }
}

// -------------------------------------------------------------------------
// Kernel FUSED: best-measured variant VERBATIM (76.8us, r10/r11). 2-wave
// (128-thread) blocks, grid 4608; waves fully decoupled (per-wave LDS slabs,
// no __syncthreads). Gather lane map (p=lane>>2, qtr=lane&3) preserved (r7:
// reordering costs 62% via coalescing loss). Chunk A = line 0 (bytes
// qtr*16), chunk B = line 1 (+64B). No setprio (r8: cost 7-10us).
// -------------------------------------------------------------------------
__global__ __launch_bounds__(128) void k_fused(
    const ushort* __restrict__ xtb, const ushort* __restrict__ wOf,
    const float* __restrict__ b_off, const ushort* __restrict__ wBf,
    const float* __restrict__ b_conv, ushort* __restrict__ yt) {
  __shared__ ushort sA[2][2][64][8];                // [wave][ks][row][j] = 4 KB
  __shared__ __align__(16) float offBuf[2][16][20]; // [wave][pl][oc(18,pad20)] = 2.5 KB

  const int bid = blockIdx.x;
  const int xcd = bid & 7;
  const int s0 = bid >> 3; // 0..575
  const int b = xcd >> 1;
  const int half = xcd & 1;
  const int th = s0 / 24; // 0..23
  const int tw = s0 % 24; // 0..23

  const int tid = threadIdx.x;
  const int wave = tid >> 6, lane = tid & 63;
  const int h0 = half * 96 + th * 4 + wave * 2; // this wave's 2-row band
  const int w0 = tw * 8;

  const int col = lane & 15, quad = lane >> 4;
  const int p = lane >> 2, qtr = lane & 3; // pixel 0..15, channel-quarter
  const int prow = p >> 3, pcol = p & 7;
  const int h = h0 + prow, w = w0 + pcol;

  // ===================== Phase 1: offset conv (per wave) =====================
  {
    float4v oacc[2];
#pragma unroll
    for (int nt = 0; nt < 2; ++nt) oacc[nt] = (float4v){0.f, 0.f, 0.f, 0.f};

    short8 oafr[2][2]; // [pb][ks] — A fragments double-buffered; weights inline

    auto oload = [&](int kk, int pb) {
      const int ky = kk / 3, kx = kk % 3;
      const int hh = h0 + (col >> 3) + ky - 1;
      const int ww = w0 + (col & 7) + kx - 1;
      const bool ok = ((unsigned)hh < (unsigned)H) && ((unsigned)ww < (unsigned)W);
      const int hhc = min(max(hh, 0), H - 1);
      const int wwc = min(max(ww, 0), W - 1);
      const ushort* pa = xtb + (((size_t)b * H + hhc) * W + wwc) * C + quad * 8;
#pragma unroll
      for (int ks = 0; ks < 2; ++ks) {
        short8 v = (short8)0;
        if (ok) v = *(const short8*)(pa + ks * 32);
        oafr[pb][ks] = v;
      }
    };

    oload(0, 0);
#pragma unroll 2 // keeps pb = kk&1 compile-time
    for (int kk = 0; kk < 9; ++kk) {
      const int pb = kk & 1;
      if (kk < 8) oload(kk + 1, pb ^ 1);
#pragma unroll
      for (int ks = 0; ks < 2; ++ks)
#pragma unroll
        for (int nt = 0; nt < 2; ++nt) {
          const short8 bw =
              *(const short8*)&wOf[((((size_t)kk * 2 + ks) * 2 + nt) * 64 + lane) * 8];
          oacc[nt] = __builtin_amdgcn_mfma_f32_16x16x32_bf16(oafr[pb][ks], bw, oacc[nt], 0, 0, 0);
        }
    }

    // distribute offsets: D[m=quad*4+r][n=nt*16+col] -> offBuf[wave][m][oc]
#pragma unroll
    for (int nt = 0; nt < 2; ++nt) {
      const int oc = nt * 16 + col;
      if (oc < OOFF) {
        const float bias = b_off[oc];
#pragma unroll
        for (int r = 0; r < 4; ++r)
          offBuf[wave][quad * 4 + r][oc] = oacc[nt][r] + bias;
      }
    }
  } // intra-wave LDS exchange: no barrier needed (same-wave ds ordering)

  // ===================== Phase 2: deformable conv =====================
  const ushort* xbase = xtb + (size_t)b * H * W * C;
  const uint qoff = (uint)qtr * 16u; // 16B slice within line 0 of the pixel
  const float hm1 = (float)(h - 1), wm1 = (float)(w - 1);

  uint offs[4];       // single-slot corner byte offsets (next kk to load)
  float4 awv;         // single-slot bilinear weights (current kk to blend)
  uint4 gA[4], gB[4]; // both chunks in flight a full kk ahead (32 VGPR)

  auto calc = [&](int kk) {
    const float2 ov = *(const float2*)&offBuf[wave][p][2 * kk];
    const int ky = kk / 3, kx = kk % 3;
    const float pyf = ov.x + hm1 + (float)ky;
    const float pxf = ov.y + wm1 + (float)kx;
    const float fy0 = floorf(pyf), fx0 = floorf(pxf);
    const float wy = pyf - fy0, wx = pxf - fx0;
    const int iy0 = (int)fy0, ix0 = (int)fx0;
    const int iy1 = iy0 + 1, ix1 = ix0 + 1;
    const bool vy0 = (unsigned)iy0 < (unsigned)H;
    const bool vy1 = (unsigned)iy1 < (unsigned)H;
    const bool vx0 = (unsigned)ix0 < (unsigned)W;
    const bool vx1 = (unsigned)ix1 < (unsigned)W;
    awv.x = (vy0 && vx0) ? (1.f - wy) * (1.f - wx) : 0.f;
    awv.y = (vy0 && vx1) ? (1.f - wy) * wx : 0.f;
    awv.z = (vy1 && vx0) ? wy * (1.f - wx) : 0.f;
    awv.w = (vy1 && vx1) ? wy * wx : 0.f;
    const int cy0 = min(max(iy0, 0), H - 1), cy1 = min(max(iy1, 0), H - 1);
    const int cx0 = min(max(ix0, 0), W - 1), cx1 = min(max(ix1, 0), W - 1);
    offs[0] = (uint)((cy0 * W + cx0) * (C * 2)) + qoff;
    offs[1] = (uint)((cy0 * W + cx1) * (C * 2)) + qoff;
    offs[2] = (uint)((cy1 * W + cx0) * (C * 2)) + qoff;
    offs[3] = (uint)((cy1 * W + cx1) * (C * 2)) + qoff;
  };

  auto loadAB = [&]() {
#pragma unroll
    for (int c = 0; c < 4; ++c)
      gA[c] = *(const uint4*)((const char*)xbase + offs[c]); // line 0 (ch 8q..)
#pragma unroll
    for (int c = 0; c < 4; ++c)
      gB[c] = *(const uint4*)((const char*)xbase + offs[c] + 64u); // line 1
  };
  auto blend = [&](const uint4* g, uint* pk) {
    const f32x2 a00 = {awv.x, awv.x};
    const f32x2 a01 = {awv.y, awv.y};
    const f32x2 a10 = {awv.z, awv.z};
    const f32x2 a11 = {awv.w, awv.w};
#pragma unroll
    for (int i = 0; i < 4; ++i) {
      f32x2 sv = upk(g[0][i]) * a00 + upk(g[1][i]) * a01 + upk(g[2][i]) * a10 + upk(g[3][i]) * a11;
      pk[i] = pk2bf(sv.x, sv.y);
    }
  };

  float4v acc[4];
#pragma unroll
  for (int nt = 0; nt < 4; ++nt) acc[nt] = (float4v){0.f, 0.f, 0.f, 0.f};

  calc(0);
  loadAB(); // kk=0 fully in flight
#pragma unroll
  for (int kk = 0; kk < 9; ++kk) {
    uint pkA[4];
    blend(gA, pkA); // chunk A = channels 8*qtr..8*qtr+7 (ks=0, k-group qtr)
    *(uint4*)&sA[wave][0][p | (qtr << 4)][0] = *(const uint4*)pkA;
    uint pkB[4];
    blend(gB, pkB); // chunk B = channels 32+8*qtr.. (ks=1, k-group qtr)
    *(uint4*)&sA[wave][1][p | (qtr << 4)][0] = *(const uint4*)pkB;

    if (kk < 8) {
      calc(kk + 1); // safe: awv/offs consumed above (single slot)
      loadAB();     // next kk fully in flight, covered by MFMA below
    }

    // intra-wave exchange: writes above, reads below, same wave => ordered.
#pragma unroll
    for (int ks = 0; ks < 2; ++ks) {
      const short8 a = *(const short8*)&sA[wave][ks][lane][0];
#pragma unroll
      for (int nt = 0; nt < 4; ++nt) {
        const short8 bb = *(const short8*)&wBf[((((size_t)kk * 2 + ks) * 4 + nt) * 64 + lane) * 8];
        acc[nt] = __builtin_amdgcn_mfma_f32_16x16x32_bf16(a, bb, acc[nt], 0, 0, 0);
      }
    }
  }

  // epilogue: yt[b][h][w][c] bf16, oc = nt + 4*(lane&15) (permuted)
  float bias[4];
#pragma unroll
  for (int nt = 0; nt < 4; ++nt) bias[nt] = b_conv[4 * col + nt];
#pragma unroll
  for (int r = 0; r < 4; ++r) {
    const int pp = quad * 4 + r; // pixel index in this wave's 2x8 band
    const int hrow = h0 + (pp >> 3), wcol = w0 + (pp & 7);
    uint2 u;
    u.x = pk2bf(acc[0][r] + bias[0], acc[1][r] + bias[1]);
    u.y = pk2bf(acc[2][r] + bias[2], acc[3][r] + bias[3]);
    *(uint2*)&yt[((size_t)(b * H + hrow) * W + wcol) * C + 4 * col] = u;
  }
}

// -------------------------------------------------------------------------
// Kernel 4 v5 — wBf via LDS. Every prior variant re-streamed the FULL
// 73.7 KB wBf per wave through the vector-memory path (4608 waves x 73.7 KB
// = 340 MB, 1152 lines/wave — the largest TA consumer; wBf > 32 KB L1 and
// waves sit at random kk phases -> L1 thrash -> L2-latency on the MFMA feed
// path). THIS REV: stage wBf ONCE per block into LDS (73.7 KB, coalesced),
// read B-fragments via ds_read_b128 (LDS pipe, separate from TA, ~low
// latency). Same bits, same (kk,ks,mt,nt) loop order -> bit-identical.
// Block shape = r2 known-good: 8 rows x 16 w, 2 rows/wave, A-frags
// double-buffered. LDS 73.7 KB -> 2 blocks/CU (~2 waves/SIMD, same as the
// old VGPR-capped occupancy; VGPR drops since bfr[] is gone).
// grid (12, 24, 4) = 1152 blocks.
// -------------------------------------------------------------------------
__global__ __launch_bounds__(256) void k_conv_main_mfma(
    const ushort* __restrict__ yt, const ushort* __restrict__ wBf,
    const float* __restrict__ b_conv, float* __restrict__ out) {
  __shared__ ushort sB[36864]; // full wBf copy = 73728 B

  const int tid = threadIdx.x;
  // ---- stage wBf -> LDS (4608 uint4, 18 per thread, coalesced) ----
  {
    const uint4* src = (const uint4*)wBf;
    uint4* dst = (uint4*)sB;
#pragma unroll
    for (int i = 0; i < 18; ++i) dst[tid + 256 * i] = src[tid + 256 * i];
  }
  __syncthreads();

  const int w0 = blockIdx.x * 16;
  const int b = blockIdx.z;
  const int wave = tid >> 6, lane = tid & 63;
  const int col = lane & 15, quad = lane >> 4;
  const int h0 = blockIdx.y * 8 + wave * 2;

  float4v acc[2][4];
#pragma unroll
  for (int mt = 0; mt < 2; ++mt)
#pragma unroll
    for (int nt = 0; nt < 4; ++nt) acc[mt][nt] = (float4v){0.f, 0.f, 0.f, 0.f};

  short8 afr[2][2][2]; // [pb][mt][ks] — A double-buffered across kk

  auto load = [&](int kk, int pb) {
    const int ky = kk / 3, kx = kk % 3;
    const int ww = w0 + col + kx - 1;
    const bool wok = (unsigned)ww < (unsigned)W;
    const int wwc = min(max(ww, 0), W - 1);
#pragma unroll
    for (int mt = 0; mt < 2; ++mt) {
      const int hh = h0 + mt + ky - 1;
      const bool ok = wok && ((unsigned)hh < (unsigned)H);
      const int hhc = min(max(hh, 0), H - 1);
      const ushort* pa = yt + (((size_t)b * H + hhc) * W + wwc) * C + quad * 8;
#pragma unroll
      for (int ks = 0; ks < 2; ++ks) {
        short8 v = (short8)0;
        if (ok) v = *(const short8*)(pa + ks * 32);
        afr[pb][mt][ks] = v;
      }
    }
  };

  load(0, 0);
#pragma unroll 2 // pb stays compile-time
  for (int kk = 0; kk < 9; ++kk) {
    const int pb = kk & 1;
    if (kk < 8) load(kk + 1, pb ^ 1);
#pragma unroll
    for (int ks = 0; ks < 2; ++ks)
#pragma unroll
      for (int nt = 0; nt < 4; ++nt) {
        const short8 bb = *(const short8*)&sB[(((kk * 2 + ks) * 4 + nt) * 64 + lane) * 8];
#pragma unroll
        for (int mt = 0; mt < 2; ++mt)
          acc[mt][nt] =
              __builtin_amdgcn_mfma_f32_16x16x32_bf16(afr[pb][mt][ks], bb, acc[mt][nt], 0, 0, 0);
      }
  }

  float bias[4];
#pragma unroll
  for (int nt = 0; nt < 4; ++nt) bias[nt] = b_conv[4 * col + nt];
#pragma unroll
  for (int mt = 0; mt < 2; ++mt) {
    const int h = h0 + mt;
#pragma unroll
    for (int nt = 0; nt < 4; ++nt) {
      const int oc = 4 * col + nt; // permuted C/D col -> oc
      float4 v;
      v.x = acc[mt][nt][0] + bias[nt];
      v.y = acc[mt][nt][1] + bias[nt];
      v.z = acc[mt][nt][2] + bias[nt];
      v.w = acc[mt][nt][3] + bias[nt];
      *(float4*)&out[(((size_t)b * O + oc) * H + h) * W + w0 + quad * 4] = v;
    }
  }
}

// -------------------------------------------------------------------------
extern "C" void kernel_launch(void* const* d_in, const int* in_sizes, int n_in,
                              void* d_out, int out_size, void* d_ws, size_t ws_size,
                              hipStream_t stream) {
  const float* x = (const float*)d_in[0];
  const float* w_off = (const float*)d_in[1];
  const float* b_off = (const float*)d_in[2];
  const float* w_conv = (const float*)d_in[3];
  const float* b_conv = (const float*)d_in[4];
  float* out = (float*)d_out;

  ushort* xtb = (ushort*)d_ws;              // B*H*W*C bf16
  ushort* yt = xtb + (size_t)B * H * W * C; // B*H*W*C bf16
  ushort* wBf = yt + (size_t)B * H * W * C; // 36864 bf16
  ushort* wOf = wBf + 36864;                // 18432 bf16

  k_pre<<<dim3(984), dim3(256), 0, stream>>>(x, xtb, w_conv, wBf, w_off, wOf);
  k_fused<<<dim3(4608), dim3(128), 0, stream>>>(xtb, wOf, b_off, wBf, b_conv, yt);
  k_conv_main_mfma<<<dim3(W / 16, H / 8, B), dim3(256), 0, stream>>>(yt, wBf, b_conv, out);
}